// Round 18
// baseline (58.639 us; speedup 1.0000x reference)
//
#include <hip/hip_runtime.h>

// GraphConv: out = d ∘ (A @ ((d∘X) @ W^T)) + b,  d = rsqrt(clip(rowsum(A),1e-6))
// B=4, N=2048, F=128. All f32 I/O, size-based binding (R6-verified).
// R16 falsified the barrier-drain theory (soft barrier == 52.2 µs): the
// counted vmcnt wait just moved to WRITET. Real constraint = HBM latency on
// A with only 2 blocks/CU of TLP. R17: split-K x2 -> 2048 blocks x 128 thr,
// 23 KB LDS -> 6 resident blocks/CU (12 waves, 6 independent barrier
// domains). f32 partials to ws; k3b reduce applies dinv/bias.
// Loop body / fragment conventions identical to R12/R16 (verified).

#define NN 2048
#define FF 128
#define ZT_OFF   32768u
#define P_OFF    (ZT_OFF + 4u * 128u * 2048u * 2u)            // 2129920
#define WS_NEED  (P_OFF + 2u * 4u * 2048u * 128u * 4u)        // + 8 MB partials

typedef __attribute__((ext_vector_type(4))) float f32x4;
typedef __attribute__((ext_vector_type(8))) short short8;

// f32 -> bf16 round-to-nearest-even (finite inputs only)
__device__ inline unsigned short f2bf(float f) {
    unsigned u = __builtin_bit_cast(unsigned, f);
    u = (u + 0x7fffu + ((u >> 16) & 1u)) >> 16;
    return (unsigned short)u;
}

__device__ inline short8 cvt8(f32x4 a, f32x4 b) {
    short8 r;
    r[0] = (short)f2bf(a.x); r[1] = (short)f2bf(a.y);
    r[2] = (short)f2bf(a.z); r[3] = (short)f2bf(a.w);
    r[4] = (short)f2bf(b.x); r[5] = (short)f2bf(b.y);
    r[6] = (short)f2bf(b.z); r[7] = (short)f2bf(b.w);
    return r;
}

// Publish LDS writes only (no vmcnt drain), raw barrier.
#define SOFT_BARRIER()                                           \
    do {                                                         \
        asm volatile("s_waitcnt lgkmcnt(0)" ::: "memory");       \
        __builtin_amdgcn_s_barrier();                            \
        asm volatile("" ::: "memory");                           \
    } while (0)

// ---- k1: dinv[row] = rsqrt(max(rowsum(A),1e-6))  [R12 verbatim] ------------
__global__ __launch_bounds__(256) void k1_deg(const float* __restrict__ A,
                                              float* __restrict__ dinv) {
    __shared__ float red[256];
    int row = blockIdx.x;
    int t = threadIdx.x;
    const f32x4* ap = (const f32x4*)(A + (size_t)row * NN);
    f32x4 v0 = ap[t];
    f32x4 v1 = ap[t + 256];
    red[t] = v0.x + v0.y + v0.z + v0.w + v1.x + v1.y + v1.z + v1.w;
    __syncthreads();
    #pragma unroll
    for (int s = 128; s > 0; s >>= 1) {
        if (t < s) red[t] += red[t + s];
        __syncthreads();
    }
    if (t == 0) dinv[row] = rsqrtf(fmaxf(red[0], 1e-6f));
}

// ---- k2: Zt[b][o][m] = bf16(dinv[b,m] * dot(X[b,m,:], W[o,:]))  [R12 verbatim]
__global__ __launch_bounds__(256) void k2_zt(const float* __restrict__ X,
                                             const float* __restrict__ W,
                                             const float* __restrict__ dinv,
                                             unsigned short* __restrict__ Zt) {
    __shared__ float Ws[FF * FF];           // 64 KB
    int blk = blockIdx.x;
    int b  = blk >> 6;                      // 0..3
    int mc = (blk >> 3) & 7;                // 0..7
    int oc = blk & 7;                       // 0..7
    int t  = threadIdx.x;
    int m  = mc * 256 + t;                  // 0..2047

    {
        f32x4* wd = (f32x4*)Ws;
        const f32x4* wsrc = (const f32x4*)W;
        #pragma unroll
        for (int j = 0; j < 16; ++j) wd[t + 256 * j] = wsrc[t + 256 * j];
    }
    __syncthreads();

    float acc[16];
    #pragma unroll
    for (int j = 0; j < 16; ++j) acc[j] = 0.f;

    const f32x4* xr = (const f32x4*)(X + ((size_t)b * NN + m) * FF);
    for (int f4 = 0; f4 < FF / 4; ++f4) {
        f32x4 xv = xr[f4];
        #pragma unroll
        for (int j = 0; j < 16; ++j) {
            f32x4 wv = *(const f32x4*)&Ws[(oc * 16 + j) * FF + f4 * 4];
            acc[j] += xv.x * wv.x + xv.y * wv.y + xv.z * wv.z + xv.w * wv.w;
        }
    }
    float dv = dinv[b * NN + m];
    #pragma unroll
    for (int j = 0; j < 16; ++j)
        Zt[((size_t)b * FF + oc * 16 + j) * NN + m] = f2bf(acc[j] * dv);
}

// ---- k3a: P[kh][b,n,o] = sum_{m in half kh} A[b,n,m]*Z[m,o] -----------------
// 2048 blocks = b(4) x ntile(128) x ohalf(2) x khalf(2); 128 threads (2 waves,
// wave w owns o [o0+w*32, +32)). BK=64, 16 iters, depth-2 named-set prefetch,
// double-buffered LDS (23 KB -> 6 blocks/CU resident), soft barriers.
__global__ __launch_bounds__(128) void k3_split(const float* __restrict__ A,
                                                const unsigned short* __restrict__ Zt,
                                                float* __restrict__ P) {
    __shared__ unsigned short As[2][16][72];    // A tile  [n][k] bf16 (4.6 KB)
    __shared__ unsigned short Zs[2][64][72];    // Z^T tile [o][k] bf16 (18.4 KB)
    int blk = blockIdx.x;                   // 0..2047
    int kh  = blk & 1;
    int o0  = ((blk >> 1) & 1) * 64;
    int n0  = ((blk >> 2) & 127) * 16;
    int b   = blk >> 9;
    int t   = threadIdx.x;                  // 0..127
    int w   = t >> 6, lane = t & 63;
    int l15 = lane & 15, kgrp = (lane >> 4) * 8;

    const float* Ab = A + (size_t)b * NN * NN + (size_t)kh * 1024;
    const unsigned short* Zb = Zt + (size_t)b * FF * NN + (size_t)kh * 1024;

    int ar = t >> 3;                        // 0..15
    int ac = (t & 7) * 8;                   // 0..56
    int zo = t >> 1;                        // 0..63
    int zk = (t & 1) * 32;                  // 0 or 32

    f32x4 acc[2];
    acc[0] = (f32x4){0.f, 0.f, 0.f, 0.f};
    acc[1] = (f32x4){0.f, 0.f, 0.f, 0.f};

    f32x4 pa0, pa1;  short8 pz0, pz1, pz2, pz3;   // set P
    f32x4 qa0, qa1;  short8 qz0, qz1, qz2, qz3;   // set Q

    #define LOADT(A0, A1, Z0, Z1, Z2, Z3, k0)                                \
        do {                                                                 \
            const float* asrc = Ab + (size_t)(n0 + ar) * NN + (k0) + ac;     \
            A0 = *(const f32x4*)asrc;                                        \
            A1 = *(const f32x4*)(asrc + 4);                                  \
            const unsigned short* zsrc = Zb + (size_t)(o0 + zo) * NN + (k0) + zk; \
            Z0 = *(const short8*)(zsrc);                                     \
            Z1 = *(const short8*)(zsrc + 8);                                 \
            Z2 = *(const short8*)(zsrc + 16);                                \
            Z3 = *(const short8*)(zsrc + 24);                                \
        } while (0)

    #define WRITET(buf, A0, A1, Z0, Z1, Z2, Z3)                              \
        do {                                                                 \
            *(short8*)&As[buf][ar][ac] = cvt8(A0, A1);                       \
            *(short8*)&Zs[buf][zo][zk]      = Z0;                            \
            *(short8*)&Zs[buf][zo][zk + 8]  = Z1;                            \
            *(short8*)&Zs[buf][zo][zk + 16] = Z2;                            \
            *(short8*)&Zs[buf][zo][zk + 24] = Z3;                            \
        } while (0)

    #define MFMAS(cur)                                                       \
        do {                                                                 \
            _Pragma("unroll")                                                \
            for (int ks = 0; ks < 64; ks += 32) {                            \
                short8 af = *(const short8*)&As[cur][l15][ks + kgrp];        \
                short8 bf0 = *(const short8*)&Zs[cur][w * 32 + l15][ks + kgrp];       \
                short8 bf1 = *(const short8*)&Zs[cur][w * 32 + 16 + l15][ks + kgrp];  \
                acc[0] = __builtin_amdgcn_mfma_f32_16x16x32_bf16(af, bf0, acc[0], 0, 0, 0); \
                acc[1] = __builtin_amdgcn_mfma_f32_16x16x32_bf16(af, bf1, acc[1], 0, 0, 0); \
            }                                                                \
        } while (0)

    LOADT(pa0, pa1, pz0, pz1, pz2, pz3, 0);
    WRITET(0, pa0, pa1, pz0, pz1, pz2, pz3);
    LOADT(pa0, pa1, pz0, pz1, pz2, pz3, 64);
    SOFT_BARRIER();

    for (int it = 0; it < 16; it += 2) {
        if (it + 2 < 16) LOADT(qa0, qa1, qz0, qz1, qz2, qz3, (it + 2) * 64);
        MFMAS(0);
        if (it + 1 < 16) WRITET(1, pa0, pa1, pz0, pz1, pz2, pz3);
        SOFT_BARRIER();
        if (it + 1 < 16) {
            if (it + 3 < 16) LOADT(pa0, pa1, pz0, pz1, pz2, pz3, (it + 3) * 64);
            MFMAS(1);
            if (it + 2 < 16) WRITET(0, qa0, qa1, qz0, qz1, qz2, qz3);
            SOFT_BARRIER();
        }
    }

    float* Pk = P + (size_t)kh * (4u * NN * FF);
    int drow = (lane >> 4) * 4;
    #pragma unroll
    for (int tt = 0; tt < 2; ++tt) {
        int o = o0 + w * 32 + tt * 16 + l15;
        #pragma unroll
        for (int r = 0; r < 4; ++r) {
            int n = n0 + drow + r;
            Pk[((size_t)b * NN + n) * FF + o] = acc[tt][r];
        }
    }
    #undef LOADT
    #undef WRITET
    #undef MFMAS
}

// ---- k3b: out = dinv * (P0 + P1) + bias  (f32x4 elementwise) ---------------
__global__ __launch_bounds__(256) void k3_reduce(const float* __restrict__ P,
                                                 const float* __restrict__ dinv,
                                                 const float* __restrict__ bias,
                                                 float* __restrict__ out) {
    int idx = blockIdx.x * 256 + threadIdx.x;     // 0..262143 (f32x4 units)
    int row = idx >> 5;                           // 0..8191 (= b*NN + n)
    int c4  = idx & 31;                           // 0..31
    const f32x4* P0 = (const f32x4*)P;
    const f32x4* P1 = P0 + (size_t)4 * NN * FF / 4;
    f32x4 p = P0[idx];
    f32x4 q = P1[idx];
    f32x4 bv = ((const f32x4*)bias)[c4];
    float dv = dinv[row];
    f32x4 r;
    r.x = (p.x + q.x) * dv + bv.x;
    r.y = (p.y + q.y) * dv + bv.y;
    r.z = (p.z + q.z) * dv + bv.z;
    r.w = (p.w + q.w) * dv + bv.w;
    ((f32x4*)out)[idx] = r;
}

extern "C" void kernel_launch(void* const* d_in, const int* in_sizes, int n_in,
                              void* d_out, int out_size, void* d_ws, size_t ws_size,
                              hipStream_t stream) {
    // Bind inputs by element count (all distinct; order-proof):
    const float *X = nullptr, *A = nullptr, *W = nullptr, *bias = nullptr;
    for (int i = 0; i < n_in; ++i) {
        switch (in_sizes[i]) {
            case 16777216: A    = (const float*)d_in[i]; break;  // [4,2048,2048]
            case 1048576:  X    = (const float*)d_in[i]; break;  // [4,2048,128]
            case 16384:    W    = (const float*)d_in[i]; break;  // [128,128]
            case 128:      bias = (const float*)d_in[i]; break;  // [128]
            default: break;
        }
    }
    float* out = (float*)d_out;
    if (!X || !A || !W || !bias) return;        // signature: absmax 0.7578125
    if (out_size != 4 * NN * FF) return;
    if (ws_size < (size_t)WS_NEED) return;      // proven >= 35.7 MB (R13/R15)

    float* dinv        = (float*)d_ws;                            // 32 KB
    unsigned short* Zt = (unsigned short*)((char*)d_ws + ZT_OFF); // 2 MB bf16
    float* P           = (float*)((char*)d_ws + P_OFF);           // 8 MB f32

    k1_deg<<<4 * NN, 256, 0, stream>>>(A, dinv);
    k2_zt<<<256, 256, 0, stream>>>(X, W, dinv, Zt);
    k3_split<<<2048, 128, 0, stream>>>(A, Zt, P);
    k3_reduce<<<1024, 256, 0, stream>>>(P, dinv, bias, out);
}

// Round 19
// 51.729 us; speedup vs baseline: 1.1336x; 1.1336x over previous
//
#include <hip/hip_runtime.h>

// GraphConv: out = d ∘ (A @ ((d∘X) @ W^T)) + b,  d = rsqrt(clip(rowsum(A),1e-6))
// B=4, N=2048, F=128. All f32 I/O, size-based binding (R6-verified).
// Falsified so far: barrier-drain (R16), TLP (R17), HBM-fetch (R13), tile
// (R14), no-LDS (R15). Cycle accounting: k3 needs >=9.2 KB of A in flight
// per CU to stream at 24.6 GB/s/CU over ~900cy latency; depth-2 sustains
// ~4-8 KB bursty with wait distance ~450cy -> stalls. R18: DEPTH-4 prefetch
// (4 named reg sets), soft barriers (no vmcnt drain — required for depth>1),
// R12 geometry/macros otherwise identical.

#define NN 2048
#define FF 128
#define WS_NEED (32768u + 4u * 128u * 2048u * 2u)   // dinv(32KB)+Zt(2MB)

typedef __attribute__((ext_vector_type(4))) float f32x4;
typedef __attribute__((ext_vector_type(8))) short short8;

// f32 -> bf16 round-to-nearest-even (finite inputs only)
__device__ inline unsigned short f2bf(float f) {
    unsigned u = __builtin_bit_cast(unsigned, f);
    u = (u + 0x7fffu + ((u >> 16) & 1u)) >> 16;
    return (unsigned short)u;
}

__device__ inline short8 cvt8(f32x4 a, f32x4 b) {
    short8 r;
    r[0] = (short)f2bf(a.x); r[1] = (short)f2bf(a.y);
    r[2] = (short)f2bf(a.z); r[3] = (short)f2bf(a.w);
    r[4] = (short)f2bf(b.x); r[5] = (short)f2bf(b.y);
    r[6] = (short)f2bf(b.z); r[7] = (short)f2bf(b.w);
    return r;
}

// Publish LDS writes only (lgkmcnt), raw barrier, NO vmcnt drain — keeps the
// depth-4 prefetch loads in flight across barriers.
#define SOFT_BARRIER()                                           \
    do {                                                         \
        asm volatile("s_waitcnt lgkmcnt(0)" ::: "memory");       \
        __builtin_amdgcn_s_barrier();                            \
        asm volatile("" ::: "memory");                           \
    } while (0)

// ---- k1: dinv[row] = rsqrt(max(rowsum(A),1e-6))  [R12 verbatim] ------------
__global__ __launch_bounds__(256) void k1_deg(const float* __restrict__ A,
                                              float* __restrict__ dinv) {
    __shared__ float red[256];
    int row = blockIdx.x;
    int t = threadIdx.x;
    const f32x4* ap = (const f32x4*)(A + (size_t)row * NN);
    f32x4 v0 = ap[t];
    f32x4 v1 = ap[t + 256];
    red[t] = v0.x + v0.y + v0.z + v0.w + v1.x + v1.y + v1.z + v1.w;
    __syncthreads();
    #pragma unroll
    for (int s = 128; s > 0; s >>= 1) {
        if (t < s) red[t] += red[t + s];
        __syncthreads();
    }
    if (t == 0) dinv[row] = rsqrtf(fmaxf(red[0], 1e-6f));
}

// ---- k2: Zt[b][o][m] = bf16(dinv[b,m] * dot(X[b,m,:], W[o,:]))  [R12 verbatim]
__global__ __launch_bounds__(256) void k2_zt(const float* __restrict__ X,
                                             const float* __restrict__ W,
                                             const float* __restrict__ dinv,
                                             unsigned short* __restrict__ Zt) {
    __shared__ float Ws[FF * FF];           // 64 KB
    int blk = blockIdx.x;
    int b  = blk >> 6;                      // 0..3
    int mc = (blk >> 3) & 7;                // 0..7
    int oc = blk & 7;                       // 0..7
    int t  = threadIdx.x;
    int m  = mc * 256 + t;                  // 0..2047

    {
        f32x4* wd = (f32x4*)Ws;
        const f32x4* wsrc = (const f32x4*)W;
        #pragma unroll
        for (int j = 0; j < 16; ++j) wd[t + 256 * j] = wsrc[t + 256 * j];
    }
    __syncthreads();

    float acc[16];
    #pragma unroll
    for (int j = 0; j < 16; ++j) acc[j] = 0.f;

    const f32x4* xr = (const f32x4*)(X + ((size_t)b * NN + m) * FF);
    for (int f4 = 0; f4 < FF / 4; ++f4) {
        f32x4 xv = xr[f4];
        #pragma unroll
        for (int j = 0; j < 16; ++j) {
            f32x4 wv = *(const f32x4*)&Ws[(oc * 16 + j) * FF + f4 * 4];
            acc[j] += xv.x * wv.x + xv.y * wv.y + xv.z * wv.z + xv.w * wv.w;
        }
    }
    float dv = dinv[b * NN + m];
    #pragma unroll
    for (int j = 0; j < 16; ++j)
        Zt[((size_t)b * FF + oc * 16 + j) * NN + m] = f2bf(acc[j] * dv);
}

// ---- k3: out[b,n,o] = dinv[b,n] * sum_m A[b,n,m]*Z[m,o] + bias[o] ----------
// R12 geometry (512 blocks, 16n x 128o, BK=64, dbuf LDS, 4 waves each owning
// 32 o) with DEPTH-4 register prefetch: tile j loads into set S(j%4); phase i
// = { issue loads tile i+4 -> S(i%4); MFMA buf(i&1); write tile i+1 (S((i+1)%4))
// -> buf((i+1)&1); soft barrier }. In flight: 3 tiles continuously.
__global__ __launch_bounds__(256) void k3_d4(const float* __restrict__ A,
                                             const unsigned short* __restrict__ Zt,
                                             const float* __restrict__ dinv,
                                             const float* __restrict__ bias,
                                             float* __restrict__ out) {
    __shared__ unsigned short As[2][16][72];    // A tile  [n][k] bf16
    __shared__ unsigned short Zs[2][128][72];   // Z^T tile [o][k] bf16
    int blk = blockIdx.x;                   // 0..511
    int b   = blk >> 7;                     // 0..3
    int n0  = (blk & 127) * 16;             // 0..2032
    int t   = threadIdx.x;
    int w   = t >> 6, lane = t & 63;
    int l15 = lane & 15, kgrp = (lane >> 4) * 8;

    const float* Ab = A + (size_t)b * NN * NN;
    const unsigned short* Zb = Zt + (size_t)b * FF * NN;

    int ar = t >> 3;                        // (t<128): 0..15
    int ac = (t & 7) * 8;                   // 0..56
    int zo = t >> 1;                        // 0..127
    int zk = (t & 1) * 32;                  // 0 or 32

    f32x4 acc[2];
    acc[0] = (f32x4){0.f, 0.f, 0.f, 0.f};
    acc[1] = (f32x4){0.f, 0.f, 0.f, 0.f};

    // four named register staging sets (rule #20: no runtime-indexed reg arrays)
    f32x4 a0_0, a0_1;  short8 z0_0, z0_1, z0_2, z0_3;   // set 0
    f32x4 a1_0, a1_1;  short8 z1_0, z1_1, z1_2, z1_3;   // set 1
    f32x4 a2_0, a2_1;  short8 z2_0, z2_1, z2_2, z2_3;   // set 2
    f32x4 a3_0, a3_1;  short8 z3_0, z3_1, z3_2, z3_3;   // set 3

    #define LOADT(A0, A1, Z0, Z1, Z2, Z3, k0)                                \
        do {                                                                 \
            if (t < 128) {                                                   \
                const float* asrc = Ab + (size_t)(n0 + ar) * NN + (k0) + ac; \
                A0 = *(const f32x4*)asrc;                                    \
                A1 = *(const f32x4*)(asrc + 4);                              \
            }                                                                \
            const unsigned short* zsrc = Zb + (size_t)zo * NN + (k0) + zk;   \
            Z0 = *(const short8*)(zsrc);                                     \
            Z1 = *(const short8*)(zsrc + 8);                                 \
            Z2 = *(const short8*)(zsrc + 16);                                \
            Z3 = *(const short8*)(zsrc + 24);                                \
        } while (0)

    #define WRITET(buf, A0, A1, Z0, Z1, Z2, Z3)                              \
        do {                                                                 \
            if (t < 128) *(short8*)&As[buf][ar][ac] = cvt8(A0, A1);          \
            *(short8*)&Zs[buf][zo][zk]      = Z0;                            \
            *(short8*)&Zs[buf][zo][zk + 8]  = Z1;                            \
            *(short8*)&Zs[buf][zo][zk + 16] = Z2;                            \
            *(short8*)&Zs[buf][zo][zk + 24] = Z3;                            \
        } while (0)

    #define MFMAS(cur)                                                       \
        do {                                                                 \
            _Pragma("unroll")                                                \
            for (int ks = 0; ks < 64; ks += 32) {                            \
                short8 af = *(const short8*)&As[cur][l15][ks + kgrp];        \
                short8 bf0 = *(const short8*)&Zs[cur][w * 32 + l15][ks + kgrp];       \
                short8 bf1 = *(const short8*)&Zs[cur][w * 32 + 16 + l15][ks + kgrp];  \
                acc[0] = __builtin_amdgcn_mfma_f32_16x16x32_bf16(af, bf0, acc[0], 0, 0, 0); \
                acc[1] = __builtin_amdgcn_mfma_f32_16x16x32_bf16(af, bf1, acc[1], 0, 0, 0); \
            }                                                                \
        } while (0)

    #define LOADS(S, k0) LOADT(a##S##_0, a##S##_1, z##S##_0, z##S##_1, z##S##_2, z##S##_3, k0)
    #define WRITES(buf, S) WRITET(buf, a##S##_0, a##S##_1, z##S##_0, z##S##_1, z##S##_2, z##S##_3)

    // prologue: tiles 0..3 into sets 0..3; tile0 -> buf0 (waits only set 0)
    LOADS(0, 0 * 64);
    LOADS(1, 1 * 64);
    LOADS(2, 2 * 64);
    LOADS(3, 3 * 64);
    WRITES(0, 0);
    SOFT_BARRIER();

    // phase i (i=0..31): load tile i+4 -> set i%4; MFMA buf(i&1);
    // write tile i+1 (set (i+1)%4) -> buf((i+1)&1); soft barrier.
    #define PHASE(I, SL, SW)                                                 \
        do {                                                                 \
            if ((I) + 4 < 32) LOADS(SL, ((I) + 4) * 64);                     \
            MFMAS((I) & 1);                                                  \
            if ((I) + 1 < 32) WRITES(((I) + 1) & 1, SW);                     \
            SOFT_BARRIER();                                                  \
        } while (0)

    for (int i = 0; i < 32; i += 4) {
        PHASE(i + 0, 0, 1);
        PHASE(i + 1, 1, 2);
        PHASE(i + 2, 2, 3);
        PHASE(i + 3, 3, 0);
    }

    int drow = (lane >> 4) * 4;
    #pragma unroll
    for (int tt = 0; tt < 2; ++tt) {
        int o = w * 32 + tt * 16 + l15;
        float bv = bias[o];
        #pragma unroll
        for (int r = 0; r < 4; ++r) {
            int n = n0 + drow + r;
            float dv = dinv[b * NN + n];
            out[((size_t)b * NN + n) * FF + o] = dv * acc[tt][r] + bv;
        }
    }
    #undef LOADT
    #undef WRITET
    #undef MFMAS
    #undef LOADS
    #undef WRITES
    #undef PHASE
}

extern "C" void kernel_launch(void* const* d_in, const int* in_sizes, int n_in,
                              void* d_out, int out_size, void* d_ws, size_t ws_size,
                              hipStream_t stream) {
    // Bind inputs by element count (all distinct; order-proof):
    const float *X = nullptr, *A = nullptr, *W = nullptr, *bias = nullptr;
    for (int i = 0; i < n_in; ++i) {
        switch (in_sizes[i]) {
            case 16777216: A    = (const float*)d_in[i]; break;  // [4,2048,2048]
            case 1048576:  X    = (const float*)d_in[i]; break;  // [4,2048,128]
            case 16384:    W    = (const float*)d_in[i]; break;  // [128,128]
            case 128:      bias = (const float*)d_in[i]; break;  // [128]
            default: break;
        }
    }
    float* out = (float*)d_out;
    if (!X || !A || !W || !bias) return;        // signature: absmax 0.7578125
    if (out_size != 4 * NN * FF) return;
    if (ws_size < (size_t)WS_NEED) return;

    float* dinv        = (float*)d_ws;                            // 32 KB
    unsigned short* Zt = (unsigned short*)((char*)d_ws + 32768);  // 2 MB bf16

    k1_deg<<<4 * NN, 256, 0, stream>>>(A, dinv);
    k2_zt<<<256, 256, 0, stream>>>(X, W, dinv, Zt);
    k3_d4<<<512, 256, 0, stream>>>(A, Zt, dinv, bias, out);
}